// Round 4
// baseline (127.783 us; speedup 1.0000x reference)
//
#include <hip/hip_runtime.h>
#include <math.h>

#define TSEQ 2048
#define NB 4
#define DM 512
#define NH 8
#define HD 64

typedef _Float16 half8 __attribute__((ext_vector_type(8)));
typedef _Float16 half4 __attribute__((ext_vector_type(4)));
typedef float floatx4 __attribute__((ext_vector_type(4)));

#if __has_builtin(__builtin_amdgcn_exp2f)
#define EXP2F(x) __builtin_amdgcn_exp2f(x)
#else
#define EXP2F(x) exp2f(x)
#endif

// async 16B global->LDS DMA (lane-linear LDS dest: uniform base + lane*16)
__device__ __forceinline__ void gl2lds16(const _Float16* g, _Float16* l) {
  const __attribute__((address_space(1))) unsigned int* gp =
      (const __attribute__((address_space(1))) unsigned int*)(uintptr_t)g;
  __attribute__((address_space(3))) unsigned int* lp =
      (__attribute__((address_space(3))) unsigned int*)(uintptr_t)l;
  __builtin_amdgcn_global_load_lds(gp, lp, 16, 0, 0);
}

// ws layout (bytes):
//   [0,         8388608)  xh      (f16 x)
//   [8650752,  10223616)  wqkvh   (f16 Wqkv)
//   [10485760, 11010048)  owh     (f16 out_w)
//   [11534336, 19922944)  qbuf
//   [20971520, 29360128)  kbuf
//   [29360128, 37748736)  vTb
//   [37748736, 46137344)  ctxh
//   [46137344, 46661632)  rope table (float2 [t][i])

__device__ __forceinline__ void cvt8(const float* __restrict__ src, char* __restrict__ dst,
                                     int unit_src, int unit_dst) {
  const float4 a = ((const float4*)src)[2 * unit_src];
  const float4 b = ((const float4*)src)[2 * unit_src + 1];
  half8 h;
  h[0] = (_Float16)a.x; h[1] = (_Float16)a.y; h[2] = (_Float16)a.z; h[3] = (_Float16)a.w;
  h[4] = (_Float16)b.x; h[5] = (_Float16)b.y; h[6] = (_Float16)b.z; h[7] = (_Float16)b.w;
  *(half8*)(dst + (size_t)unit_dst * 16) = h;
}

// units of 16B: xh 524288 | wqkvh 98304 | owh 32768 | rope 32768  = 688128 total
__global__ void prep(const float* __restrict__ x, const float* __restrict__ wqkv,
                     const float* __restrict__ ow, char* __restrict__ ws) {
  const int i = blockIdx.x * 256 + threadIdx.x;   // grid exactly covers 688128
  if (i < 524288) {                         // xh
    cvt8(x, ws, i, i);
  } else if (i < 622592) {                  // wqkvh
    const int o = i - 524288;
    cvt8(wqkv, ws + 8650752, o, o);
  } else if (i < 655360) {                  // owh
    const int o = i - 622592;
    cvt8(ow, ws + 10485760, o, o);
  } else {                                  // rope table: 2 entries per 16B unit
    const int u = i - 655360;
    float4 o4;
    {
      const int id = 2 * u, t = id >> 5, fi = id & 31;
      const float invf = powf(10000.0f, -(float)(2 * fi) * (1.0f / 64.0f));
      float s, c; sincosf((float)t * invf, &s, &c);
      o4.x = c; o4.y = s;
    }
    {
      const int id = 2 * u + 1, t = id >> 5, fi = id & 31;
      const float invf = powf(10000.0f, -(float)(2 * fi) * (1.0f / 64.0f));
      float s, c; sincosf((float)t * invf, &s, &c);
      o4.z = c; o4.w = s;
    }
    ((float4*)(ws + 46137344))[u] = o4;
  }
}

// ---------------- QKV GEMM (f16 MFMA) + fused RoPE -----------------------------
// R8 (kept): double-buffered LDS pipeline; stage of tile k+1 issued before the
// compute of tile k; one barrier per 32-K-step.
__global__ __launch_bounds__(256) void qkv_gemm_mfma(
    const _Float16* __restrict__ A, const _Float16* __restrict__ B,
    const float2* __restrict__ rope,
    _Float16* __restrict__ qb, _Float16* __restrict__ kb, _Float16* __restrict__ vT)
{
  __shared__ __align__(16) _Float16 As0[128 * 32];
  __shared__ __align__(16) _Float16 Bs0[128 * 32];
  __shared__ __align__(16) _Float16 As1[128 * 32];
  __shared__ __align__(16) _Float16 Bs1[128 * 32];
  const int tid = threadIdx.x;
  const int wv = tid >> 6, lane = tid & 63, quad = lane >> 4, col = lane & 15;
  const int wm = wv >> 1, we = wv & 1;
  const int m0 = blockIdx.x << 7, c0 = blockIdx.y << 7;
  const int r0 = tid >> 2, p0 = tid & 3;
  const int cA0 = (p0 - (r0 >> 1)) & 3;
  const int r1 = (tid + 256) >> 2, p1 = tid & 3;
  const int cA1 = (p1 - (r1 >> 1)) & 3;
  const _Float16* ga0 = &A[(size_t)(m0 + r0) * DM + cA0 * 8];
  const _Float16* ga1 = &A[(size_t)(m0 + r1) * DM + cA1 * 8];
  const _Float16* gb0 = &B[(size_t)(c0 + r0) * DM + cA0 * 8];
  const _Float16* gb1 = &B[(size_t)(c0 + r1) * DM + cA1 * 8];
  floatx4 acc[4][4] = {};   // [mt][et]

#define QKV_STAGE(AS, BS, K)                      \
  do {                                            \
    gl2lds16(ga0 + (K), &AS[tid * 8]);            \
    gl2lds16(ga1 + (K), &AS[(tid + 256) * 8]);    \
    gl2lds16(gb0 + (K), &BS[tid * 8]);            \
    gl2lds16(gb1 + (K), &BS[(tid + 256) * 8]);    \
  } while (0)

#define QKV_COMPUTE(AS, BS)                                                   \
  do {                                                                        \
    half8 af[4], bf[4];                                                       \
    _Pragma("unroll") for (int mt = 0; mt < 4; mt++) {                        \
      const int R = wm * 64 + mt * 16 + col;                                  \
      af[mt] = *(const half8*)&AS[R * 32 + (((quad + (R >> 1)) & 3) << 3)];   \
    }                                                                         \
    _Pragma("unroll") for (int et = 0; et < 4; et++) {                        \
      const int R = we * 64 + et * 16 + col;                                  \
      bf[et] = *(const half8*)&BS[R * 32 + (((quad + (R >> 1)) & 3) << 3)];   \
    }                                                                         \
    _Pragma("unroll") for (int mt = 0; mt < 4; mt++)                          \
      _Pragma("unroll") for (int et = 0; et < 4; et++)                        \
        acc[mt][et] =                                                         \
            __builtin_amdgcn_mfma_f32_16x16x32_f16(af[mt], bf[et], acc[mt][et], 0, 0, 0); \
  } while (0)

  QKV_STAGE(As0, Bs0, 0);       // prologue: tile 0 in flight
  for (int k0 = 0; k0 < DM; k0 += 64) {
    __syncthreads();                    // buf0(k0) landed & visible; prev reads done
    QKV_STAGE(As1, Bs1, k0 + 32);       // next tile flies under compute below
    QKV_COMPUTE(As0, Bs0);
    __syncthreads();                    // buf1 landed & visible; buf0 reads done
    if (k0 + 64 < DM) QKV_STAGE(As0, Bs0, k0 + 64);
    QKV_COMPUTE(As1, Bs1);
  }
#undef QKV_STAGE
#undef QKV_COMPUTE

  const int eidx = (c0 >> 6) + we;            // 0..23, wave-uniform
  const int three = eidx >> 3, h = eidx & 7;
  const int mbase = m0 + wm * 64 + quad * 4;
  if (three == 2) {
#pragma unroll
    for (int mt = 0; mt < 4; mt++) {
      const int m = mbase + mt * 16;
      const int n = m >> 11, t = m & 2047;
#pragma unroll
      for (int et = 0; et < 4; et++) {
        const int dh = et * 16 + col;
        half4 hv;
#pragma unroll
        for (int r = 0; r < 4; r++) hv[r] = (_Float16)acc[mt][et][r];
        *(half4*)&vT[(size_t)(n * NH + h) * HD * TSEQ + (size_t)dh * TSEQ + t] = hv;
      }
    }
  } else {
    _Float16* dst = three ? kb : qb;
    // q scale = (1/8) * log2(e) so attention's exp is a bare v_exp_f32
    const float scl = three ? 1.0f : 0.125f * 1.4426950408889634f;
#pragma unroll
    for (int mt = 0; mt < 4; mt++)
#pragma unroll
      for (int r = 0; r < 4; r++) {
        const int m = mbase + mt * 16 + r;
        const int n = m >> 11, t = m & 2047;
#pragma unroll
        for (int et = 0; et < 4; et++) {
          const int i = ((et & 1) << 4) + col;
          const float2 cs = rope[t * 32 + i];
          const float v = acc[mt][et][r];
          const float v2 = acc[mt][et ^ 2][r];
          const float o = (et < 2) ? (v * cs.x - v2 * cs.y) : (v * cs.x + v2 * cs.y);
          dst[((size_t)(n * NH + h) * TSEQ + t) * HD + et * 16 + col] = (_Float16)(o * scl);
        }
      }
  }
}

// ---------------- windowed flash attention, shift-free softmax ----------------
// R9: double-buffered K/V staging -> ONE barrier per k-tile (was 2). The write
// of the prefetched regs goes into buf p^1 AFTER computing from buf p, so no
// write-after-read barrier is needed; the single end-of-iter barrier provides
// both "writes visible" and "reads done" for the next iteration. Osh aliases
// Ps (Ps dead after the k-loop; both wave-private-row disciplined). LDS 45 KB
// -> 3 blocks/CU (12 waves/CU). Barriers per block: 10 -> 6.
__global__ __launch_bounds__(256, 4) void attn_win_mfma(
    const _Float16* __restrict__ qb, const _Float16* __restrict__ kb,
    const _Float16* __restrict__ vT, _Float16* __restrict__ ctx)
{
  __shared__ __align__(16) char smem[46080];
  _Float16* const KsA = (_Float16*)smem;               // [64][72] j-major
  _Float16* const VtA = (_Float16*)(smem + 9216);      // [64][72] d-major
  _Float16* const KsB = (_Float16*)(smem + 18432);
  _Float16* const VtB = (_Float16*)(smem + 27648);
  _Float16* const Ps  = (_Float16*)(smem + 36864);     // [64][72]; Osh aliases
  _Float16* const Osh = Ps;

  const int tid = threadIdx.x;
  const int wv = tid >> 6;
  const int lane = tid & 63;
  const int quad = lane >> 4;
  const int col = lane & 15;
  const int nh = blockIdx.y;
  const int q0 = blockIdx.x << 6;
  const _Float16* qp = qb + (size_t)nh * TSEQ * HD;
  const _Float16* kp = kb + (size_t)nh * TSEQ * HD;
  const _Float16* vp = vT + (size_t)nh * HD * TSEQ;

  const int i_row = (wv << 4) + col;
  const int ig = q0 + i_row;
  const half8 qf0 = *(const half8*)&qp[(size_t)ig * HD + (quad << 3)];
  const half8 qf1 = *(const half8*)&qp[(size_t)ig * HD + 32 + (quad << 3)];

  float l_i = 0.0f;          // per-lane partial sum of p
  floatx4 accO[4] = {};

  const int kt0 = max(0, q0 - 127) >> 6;
  const int kt1 = min(TSEQ - 1, q0 + 191) >> 6;
  const int kr = tid >> 2, kc = (tid & 3) << 4;      // staging: row, 16-col chunk
  const _Float16* kpr = kp + (size_t)kr * HD + kc;   // + j0*HD selects K tile
  const _Float16* vpr = vp + (size_t)kr * TSEQ + kc; // + j0 selects V^T tile

  // prologue: tile kt0 -> buffer A
  {
    const int j0 = kt0 << 6;
    *(half8*)&KsA[kr * 72 + kc]     = *(const half8*)(kpr + (size_t)j0 * HD);
    *(half8*)&KsA[kr * 72 + kc + 8] = *(const half8*)(kpr + (size_t)j0 * HD + 8);
    *(half8*)&VtA[kr * 72 + kc]     = *(const half8*)(vpr + j0);
    *(half8*)&VtA[kr * 72 + kc + 8] = *(const half8*)(vpr + j0 + 8);
  }
  __syncthreads();

  int p = 0;
  for (int kt = kt0; kt <= kt1; kt++) {
    const int j0 = kt << 6;
    const _Float16* Ksc = p ? KsB : KsA;
    const _Float16* Vtc = p ? VtB : VtA;
    _Float16* Ksn = p ? KsA : KsB;
    _Float16* Vtn = p ? VtA : VtB;
    const bool more = (kt < kt1);      // wave-uniform

    // issue prefetch of next tile into regs; latency hides under compute below
    half8 nk0, nk1, nv0, nv1;
    if (more) {
      const int jn = j0 + 64;
      nk0 = *(const half8*)(kpr + (size_t)jn * HD);
      nk1 = *(const half8*)(kpr + (size_t)jn * HD + 8);
      nv0 = *(const half8*)(vpr + jn);
      nv1 = *(const half8*)(vpr + jn + 8);
    }

    // S^T[j][i]: A = K rows, B = Q^T. C-layout: row=j_local, col=i(=our query)
    floatx4 S[4];
#pragma unroll
    for (int js = 0; js < 4; js++) {
      const half8 a0 = *(const half8*)&Ksc[((js << 4) + col) * 72 + (quad << 3)];
      const half8 a1 = *(const half8*)&Ksc[((js << 4) + col) * 72 + 32 + (quad << 3)];
      floatx4 c = {0.f, 0.f, 0.f, 0.f};
      c = __builtin_amdgcn_mfma_f32_16x16x32_f16(a0, qf0, c, 0, 0, 0);
      c = __builtin_amdgcn_mfma_f32_16x16x32_f16(a1, qf1, c, 0, 0, 0);
      S[js] = c;
    }
    // mask -> p = exp2(s) (q carries log2e/8); masked p = 0. No max, no rescale.
    // window test: j in [ig-127, ig+128]  <=>  (unsigned)(j - ig + 127) < 256
    const int relb = j0 - ig + 127 + (quad << 2);
#pragma unroll
    for (int js = 0; js < 4; js++) {
      half4 ph;
#pragma unroll
      for (int r = 0; r < 4; r++) {
        const bool valid = (unsigned)(relb + (js << 4) + r) < 256u;
        const float pv_ = valid ? EXP2F(S[js][r]) : 0.0f;
        l_i += pv_;
        ph[r] = (_Float16)pv_;
      }
      *(half4*)&Ps[i_row * 72 + (js << 4) + (quad << 2)] = ph;
    }
    // PV directly: Ps rows are wave-private; same-wave LDS ordering suffices.
    const half8 pa0 = *(const half8*)&Ps[i_row * 72 + (quad << 3)];
    const half8 pa1 = *(const half8*)&Ps[i_row * 72 + 32 + (quad << 3)];
#pragma unroll
    for (int d4 = 0; d4 < 4; d4++) {
      const half8 vb0 = *(const half8*)&Vtc[((d4 << 4) + col) * 72 + (quad << 3)];
      const half8 vb1 = *(const half8*)&Vtc[((d4 << 4) + col) * 72 + 32 + (quad << 3)];
      accO[d4] = __builtin_amdgcn_mfma_f32_16x16x32_f16(pa0, vb0, accO[d4], 0, 0, 0);
      accO[d4] = __builtin_amdgcn_mfma_f32_16x16x32_f16(pa1, vb1, accO[d4], 0, 0, 0);
    }

    // stage the prefetched tile into the other buffer (disjoint from Ksc/Vtc:
    // safe while other waves still compute this tile), then ONE barrier.
    if (more) {
      *(half8*)&Ksn[kr * 72 + kc]     = nk0;
      *(half8*)&Ksn[kr * 72 + kc + 8] = nk1;
      *(half8*)&Vtn[kr * 72 + kc]     = nv0;
      *(half8*)&Vtn[kr * 72 + kc + 8] = nv1;
    }
    __syncthreads();
    p ^= 1;
  }
  // one cross-lane l reduction for the whole kernel (lanes sharing col = query)
  l_i += __shfl_xor(l_i, 16, 64);
  l_i += __shfl_xor(l_i, 32, 64);
  {
    const float linv = 1.0f / l_i;
    float l4[4];
#pragma unroll
    for (int r = 0; r < 4; r++) l4[r] = __shfl(linv, (quad << 2) + r, 64);
#pragma unroll
    for (int d4 = 0; d4 < 4; d4++)
#pragma unroll
      for (int r = 0; r < 4; r++)
        Osh[((wv << 4) + (quad << 2) + r) * 72 + (d4 << 4) + col] = (_Float16)(accO[d4][r] * l4[r]);
  }
  __syncthreads();
  {
    const int n = nh >> 3, h = nh & 7;
    const int oi = tid >> 2, oc = (tid & 3) << 4;
    _Float16* dst = &ctx[((size_t)n * TSEQ + q0 + oi) * DM + h * HD + oc];
    *(half8*)&dst[0] = *(const half8*)&Osh[oi * 72 + oc];
    *(half8*)&dst[8] = *(const half8*)&Osh[oi * 72 + oc + 8];
  }
}

// ---------------- output projection (f16 MFMA) + bias, f32 out ------------------
// R8 (kept): register prefetch of next K-step's global loads issued before
// compute so HBM/L2 latency hides under fragment reads + MFMA.
__global__ __launch_bounds__(256) void out_gemm_mfma(
    const _Float16* __restrict__ A, const _Float16* __restrict__ B,
    const float* __restrict__ bias, float* __restrict__ out)
{
  __shared__ _Float16 As[128 * 40];
  __shared__ _Float16 Bs[64 * 40];
  const int tid = threadIdx.x;
  const int wv = tid >> 6, lane = tid & 63, quad = lane >> 4, col = lane & 15;
  const int wm = wv >> 1, we = wv & 1;
  const int m0 = blockIdx.x << 7, c0 = blockIdx.y << 6;
  const int sr = tid >> 1, sc = (tid & 1) << 4;
  const int br = tid >> 2, bc = (tid & 3) << 3;
  const _Float16* ap = &A[(size_t)(m0 + sr) * DM + sc];
  const _Float16* bp = &B[(size_t)(c0 + br) * DM + bc];
  floatx4 acc[4][2] = {};
  half8 a0 = *(const half8*)(ap);
  half8 a1 = *(const half8*)(ap + 8);
  half8 b0 = *(const half8*)(bp);
  for (int k0 = 0; k0 < DM; k0 += 32) {
    __syncthreads();
    *(half8*)&As[sr * 40 + sc] = a0;
    *(half8*)&As[sr * 40 + sc + 8] = a1;
    *(half8*)&Bs[br * 40 + bc] = b0;
    half8 an0, an1, bn0;
    const bool more = (k0 + 32 < DM);
    if (more) {
      an0 = *(const half8*)(ap + k0 + 32);
      an1 = *(const half8*)(ap + k0 + 40);
      bn0 = *(const half8*)(bp + k0 + 32);
    }
    __syncthreads();
    half8 af[4], bf[2];
#pragma unroll
    for (int mt = 0; mt < 4; mt++)
      af[mt] = *(const half8*)&As[(wm * 64 + mt * 16 + col) * 40 + quad * 8];
#pragma unroll
    for (int et = 0; et < 2; et++)
      bf[et] = *(const half8*)&Bs[(we * 32 + et * 16 + col) * 40 + quad * 8];
#pragma unroll
    for (int mt = 0; mt < 4; mt++)
#pragma unroll
      for (int et = 0; et < 2; et++)
        acc[mt][et] = __builtin_amdgcn_mfma_f32_16x16x32_f16(af[mt], bf[et], acc[mt][et], 0, 0, 0);
    if (more) { a0 = an0; a1 = an1; b0 = bn0; }
  }
  float bb[2];
#pragma unroll
  for (int et = 0; et < 2; et++) bb[et] = bias[c0 + we * 32 + et * 16 + col];
  const int mbase = m0 + wm * 64 + quad * 4;
#pragma unroll
  for (int mt = 0; mt < 4; mt++)
#pragma unroll
    for (int r = 0; r < 4; r++) {
      const int m = mbase + mt * 16 + r;
#pragma unroll
      for (int et = 0; et < 2; et++)
        out[(size_t)m * DM + c0 + we * 32 + et * 16 + col] = acc[mt][et][r] + bb[et];
    }
}

extern "C" void kernel_launch(void* const* d_in, const int* in_sizes, int n_in,
                              void* d_out, int out_size, void* d_ws, size_t ws_size,
                              hipStream_t stream) {
  const float* x    = (const float*)d_in[0];
  const float* wqkv = (const float*)d_in[1];
  const float* ow   = (const float*)d_in[2];
  const float* ob   = (const float*)d_in[3];
  char* ws = (char*)d_ws;
  _Float16* xh    = (_Float16*)(ws);               //  8,388,608 B
  _Float16* wqkvh = (_Float16*)(ws + 8650752);     //  1,572,864 B
  _Float16* owh   = (_Float16*)(ws + 10485760);    //    524,288 B
  _Float16* qbuf  = (_Float16*)(ws + 11534336);    //  8,388,608 B
  _Float16* kbuf  = (_Float16*)(ws + 20971520);    //  8,388,608 B
  _Float16* vTb   = (_Float16*)(ws + 29360128);    //  8,388,608 B
  _Float16* ctxh  = (_Float16*)(ws + 37748736);    //  8,388,608 B
  float2*   rope  = (float2*)  (ws + 46137344);    //    524,288 B -> end 46,661,632

  prep<<<2688, 256, 0, stream>>>(x, wqkv, ow, ws);        // 688128 16B-units, 1/thread
  qkv_gemm_mfma<<<dim3(64, 12), 256, 0, stream>>>(xh, wqkvh, rope, qbuf, kbuf, vTb);
  attn_win_mfma<<<dim3(32, 32), 256, 0, stream>>>(qbuf, kbuf, vTb, ctxh);
  out_gemm_mfma<<<dim3(64, 8), 256, 0, stream>>>(ctxh, owh, ob, (float*)d_out);
}

// Round 5
// 123.517 us; speedup vs baseline: 1.0345x; 1.0345x over previous
//
#include <hip/hip_runtime.h>
#include <math.h>

#define TSEQ 2048
#define NB 4
#define DM 512
#define NH 8
#define HD 64

typedef _Float16 half8 __attribute__((ext_vector_type(8)));
typedef _Float16 half4 __attribute__((ext_vector_type(4)));
typedef float floatx4 __attribute__((ext_vector_type(4)));

#if __has_builtin(__builtin_amdgcn_exp2f)
#define EXP2F(x) __builtin_amdgcn_exp2f(x)
#else
#define EXP2F(x) exp2f(x)
#endif

// async 16B global->LDS DMA (lane-linear LDS dest: uniform base + lane*16)
__device__ __forceinline__ void gl2lds16(const _Float16* g, _Float16* l) {
  const __attribute__((address_space(1))) unsigned int* gp =
      (const __attribute__((address_space(1))) unsigned int*)(uintptr_t)g;
  __attribute__((address_space(3))) unsigned int* lp =
      (__attribute__((address_space(3))) unsigned int*)(uintptr_t)l;
  __builtin_amdgcn_global_load_lds(gp, lp, 16, 0, 0);
}

// ws layout (bytes):
//   [0,         8388608)  xh      (f16 x)
//   [8650752,  10223616)  wqkvh   (f16 Wqkv)
//   [10485760, 11010048)  owh     (f16 out_w)
//   [11534336, 19922944)  qbuf
//   [20971520, 29360128)  kbuf
//   [29360128, 37748736)  vTb
//   [37748736, 46137344)  ctxh
//   [46137344, 46661632)  rope table (float2 [t][i])

__device__ __forceinline__ void cvt8(const float* __restrict__ src, char* __restrict__ dst,
                                     int unit_src, int unit_dst) {
  const float4 a = ((const float4*)src)[2 * unit_src];
  const float4 b = ((const float4*)src)[2 * unit_src + 1];
  half8 h;
  h[0] = (_Float16)a.x; h[1] = (_Float16)a.y; h[2] = (_Float16)a.z; h[3] = (_Float16)a.w;
  h[4] = (_Float16)b.x; h[5] = (_Float16)b.y; h[6] = (_Float16)b.z; h[7] = (_Float16)b.w;
  *(half8*)(dst + (size_t)unit_dst * 16) = h;
}

// units of 16B: xh 524288 | wqkvh 98304 | owh 32768 | rope 32768  = 688128 total
__global__ void prep(const float* __restrict__ x, const float* __restrict__ wqkv,
                     const float* __restrict__ ow, char* __restrict__ ws) {
  const int i = blockIdx.x * 256 + threadIdx.x;   // grid exactly covers 688128
  if (i < 524288) {                         // xh
    cvt8(x, ws, i, i);
  } else if (i < 622592) {                  // wqkvh
    const int o = i - 524288;
    cvt8(wqkv, ws + 8650752, o, o);
  } else if (i < 655360) {                  // owh
    const int o = i - 622592;
    cvt8(ow, ws + 10485760, o, o);
  } else {                                  // rope table: 2 entries per 16B unit
    const int u = i - 655360;
    float4 o4;
    {
      const int id = 2 * u, t = id >> 5, fi = id & 31;
      const float invf = powf(10000.0f, -(float)(2 * fi) * (1.0f / 64.0f));
      float s, c; sincosf((float)t * invf, &s, &c);
      o4.x = c; o4.y = s;
    }
    {
      const int id = 2 * u + 1, t = id >> 5, fi = id & 31;
      const float invf = powf(10000.0f, -(float)(2 * fi) * (1.0f / 64.0f));
      float s, c; sincosf((float)t * invf, &s, &c);
      o4.z = c; o4.w = s;
    }
    ((float4*)(ws + 46137344))[u] = o4;
  }
}

// ---------------- QKV GEMM (f16 MFMA) + fused RoPE -----------------------------
// R8 (kept): double-buffered LDS pipeline; stage of tile k+1 issued before the
// compute of tile k; one barrier per 32-K-step.
__global__ __launch_bounds__(256) void qkv_gemm_mfma(
    const _Float16* __restrict__ A, const _Float16* __restrict__ B,
    const float2* __restrict__ rope,
    _Float16* __restrict__ qb, _Float16* __restrict__ kb, _Float16* __restrict__ vT)
{
  __shared__ __align__(16) _Float16 As0[128 * 32];
  __shared__ __align__(16) _Float16 Bs0[128 * 32];
  __shared__ __align__(16) _Float16 As1[128 * 32];
  __shared__ __align__(16) _Float16 Bs1[128 * 32];
  const int tid = threadIdx.x;
  const int wv = tid >> 6, lane = tid & 63, quad = lane >> 4, col = lane & 15;
  const int wm = wv >> 1, we = wv & 1;
  const int m0 = blockIdx.x << 7, c0 = blockIdx.y << 7;
  const int r0 = tid >> 2, p0 = tid & 3;
  const int cA0 = (p0 - (r0 >> 1)) & 3;
  const int r1 = (tid + 256) >> 2, p1 = tid & 3;
  const int cA1 = (p1 - (r1 >> 1)) & 3;
  const _Float16* ga0 = &A[(size_t)(m0 + r0) * DM + cA0 * 8];
  const _Float16* ga1 = &A[(size_t)(m0 + r1) * DM + cA1 * 8];
  const _Float16* gb0 = &B[(size_t)(c0 + r0) * DM + cA0 * 8];
  const _Float16* gb1 = &B[(size_t)(c0 + r1) * DM + cA1 * 8];
  floatx4 acc[4][4] = {};   // [mt][et]

#define QKV_STAGE(AS, BS, K)                      \
  do {                                            \
    gl2lds16(ga0 + (K), &AS[tid * 8]);            \
    gl2lds16(ga1 + (K), &AS[(tid + 256) * 8]);    \
    gl2lds16(gb0 + (K), &BS[tid * 8]);            \
    gl2lds16(gb1 + (K), &BS[(tid + 256) * 8]);    \
  } while (0)

#define QKV_COMPUTE(AS, BS)                                                   \
  do {                                                                        \
    half8 af[4], bf[4];                                                       \
    _Pragma("unroll") for (int mt = 0; mt < 4; mt++) {                        \
      const int R = wm * 64 + mt * 16 + col;                                  \
      af[mt] = *(const half8*)&AS[R * 32 + (((quad + (R >> 1)) & 3) << 3)];   \
    }                                                                         \
    _Pragma("unroll") for (int et = 0; et < 4; et++) {                        \
      const int R = we * 64 + et * 16 + col;                                  \
      bf[et] = *(const half8*)&BS[R * 32 + (((quad + (R >> 1)) & 3) << 3)];   \
    }                                                                         \
    _Pragma("unroll") for (int mt = 0; mt < 4; mt++)                          \
      _Pragma("unroll") for (int et = 0; et < 4; et++)                        \
        acc[mt][et] =                                                         \
            __builtin_amdgcn_mfma_f32_16x16x32_f16(af[mt], bf[et], acc[mt][et], 0, 0, 0); \
  } while (0)

  QKV_STAGE(As0, Bs0, 0);       // prologue: tile 0 in flight
  for (int k0 = 0; k0 < DM; k0 += 64) {
    __syncthreads();                    // buf0(k0) landed & visible; prev reads done
    QKV_STAGE(As1, Bs1, k0 + 32);       // next tile flies under compute below
    QKV_COMPUTE(As0, Bs0);
    __syncthreads();                    // buf1 landed & visible; buf0 reads done
    if (k0 + 64 < DM) QKV_STAGE(As0, Bs0, k0 + 64);
    QKV_COMPUTE(As1, Bs1);
  }
#undef QKV_STAGE
#undef QKV_COMPUTE

  const int eidx = (c0 >> 6) + we;            // 0..23, wave-uniform
  const int three = eidx >> 3, h = eidx & 7;
  const int mbase = m0 + wm * 64 + quad * 4;
  if (three == 2) {
#pragma unroll
    for (int mt = 0; mt < 4; mt++) {
      const int m = mbase + mt * 16;
      const int n = m >> 11, t = m & 2047;
#pragma unroll
      for (int et = 0; et < 4; et++) {
        const int dh = et * 16 + col;
        half4 hv;
#pragma unroll
        for (int r = 0; r < 4; r++) hv[r] = (_Float16)acc[mt][et][r];
        *(half4*)&vT[(size_t)(n * NH + h) * HD * TSEQ + (size_t)dh * TSEQ + t] = hv;
      }
    }
  } else {
    _Float16* dst = three ? kb : qb;
    // q scale = (1/8) * log2(e) so attention's exp is a bare v_exp_f32
    const float scl = three ? 1.0f : 0.125f * 1.4426950408889634f;
#pragma unroll
    for (int mt = 0; mt < 4; mt++)
#pragma unroll
      for (int r = 0; r < 4; r++) {
        const int m = mbase + mt * 16 + r;
        const int n = m >> 11, t = m & 2047;
#pragma unroll
        for (int et = 0; et < 4; et++) {
          const int i = ((et & 1) << 4) + col;
          const float2 cs = rope[t * 32 + i];
          const float v = acc[mt][et][r];
          const float v2 = acc[mt][et ^ 2][r];
          const float o = (et < 2) ? (v * cs.x - v2 * cs.y) : (v * cs.x + v2 * cs.y);
          dst[((size_t)(n * NH + h) * TSEQ + t) * HD + et * 16 + col] = (_Float16)(o * scl);
        }
      }
  }
}

// ---------------- windowed flash attention, shift-free softmax ----------------
// R3 structure restored (R4's single-barrier dbuf regressed: 45KB LDS dropped
// occupancy 4->3 blocks/CU and staging moved onto the pre-barrier critical
// path). R10 adds an XCD-aware block swizzle (T1): 1024 blocks, 8 XCDs, each
// XCD gets 128 contiguous (head, q-tile) blocks = 4 complete batch-heads, so
// the shared K/V window (~2MB per XCD chunk) becomes L2-resident instead of
// streaming ~16MB through every XCD's private L2. 1024%8==0 -> bijective.
__global__ __launch_bounds__(256, 4) void attn_win_mfma(
    const _Float16* __restrict__ qb, const _Float16* __restrict__ kb,
    const _Float16* __restrict__ vT, _Float16* __restrict__ ctx)
{
  __shared__ __align__(16) char smem[36864];
  _Float16* Ks = (_Float16*)smem;              // [64][72] j-major
  _Float16* Vt = (_Float16*)(smem + 9216);     // [64][72] d-major (from vT global)
  _Float16* Ps = (_Float16*)(smem + 18432);    // [64][72] i-major (wave-private rows)
  _Float16* Osh = (_Float16*)(smem + 27648);   // [64][72] dedicated

  const int tid = threadIdx.x;
  const int wv = tid >> 6;
  const int lane = tid & 63;
  const int quad = lane >> 4;
  const int col = lane & 15;
  // XCD swizzle: lin%8 = XCD -> give each XCD a contiguous 128-block chunk
  const int lin = (blockIdx.y << 5) | blockIdx.x;
  const int sl  = ((lin & 7) << 7) | (lin >> 3);
  const int nh = sl >> 5;
  const int q0 = (sl & 31) << 6;
  const _Float16* qp = qb + (size_t)nh * TSEQ * HD;
  const _Float16* kp = kb + (size_t)nh * TSEQ * HD;
  const _Float16* vp = vT + (size_t)nh * HD * TSEQ;

  const int i_row = (wv << 4) + col;
  const int ig = q0 + i_row;
  const half8 qf0 = *(const half8*)&qp[(size_t)ig * HD + (quad << 3)];
  const half8 qf1 = *(const half8*)&qp[(size_t)ig * HD + 32 + (quad << 3)];

  float l_i = 0.0f;          // per-lane partial sum of p
  floatx4 accO[4] = {};

  const int kt0 = max(0, q0 - 127) >> 6;
  const int kt1 = min(TSEQ - 1, q0 + 191) >> 6;
  const int kr = tid >> 2, kc = (tid & 3) << 4;    // K: row j, col d
  const int vd = tid >> 2, vc = (tid & 3) << 4;    // V^T: row d, col j
  const _Float16* kpr = kp + (size_t)kr * HD + kc; // + j0*HD selects the tile
  const _Float16* vpr = vp + (size_t)vd * TSEQ + vc; // + j0 selects the tile

  // prologue: load first tile into registers
  half8 ck0 = *(const half8*)(kpr + (size_t)(kt0 << 6) * HD);
  half8 ck1 = *(const half8*)(kpr + (size_t)(kt0 << 6) * HD + 8);
  half8 cv0 = *(const half8*)(vpr + (kt0 << 6));
  half8 cv1 = *(const half8*)(vpr + (kt0 << 6) + 8);

  for (int kt = kt0; kt <= kt1; kt++) {
    const int j0 = kt << 6;
    __syncthreads();   // previous iteration's LDS reads complete
    *(half8*)&Ks[kr * 72 + kc] = ck0;
    *(half8*)&Ks[kr * 72 + kc + 8] = ck1;
    *(half8*)&Vt[vd * 72 + vc] = cv0;
    *(half8*)&Vt[vd * 72 + vc + 8] = cv1;
    __syncthreads();   // staging visible

    // prefetch NEXT tile into registers; latency hides under compute below.
    {
      const int jn = (kt < kt1) ? (j0 + 64) : j0;
      ck0 = *(const half8*)(kpr + (size_t)jn * HD);
      ck1 = *(const half8*)(kpr + (size_t)jn * HD + 8);
      cv0 = *(const half8*)(vpr + jn);
      cv1 = *(const half8*)(vpr + jn + 8);
    }

    // S^T[j][i]: A = K rows, B = Q^T. C-layout: row=j_local, col=i(=our query)
    floatx4 S[4];
#pragma unroll
    for (int js = 0; js < 4; js++) {
      const half8 a0 = *(const half8*)&Ks[((js << 4) + col) * 72 + (quad << 3)];
      const half8 a1 = *(const half8*)&Ks[((js << 4) + col) * 72 + 32 + (quad << 3)];
      floatx4 c = {0.f, 0.f, 0.f, 0.f};
      c = __builtin_amdgcn_mfma_f32_16x16x32_f16(a0, qf0, c, 0, 0, 0);
      c = __builtin_amdgcn_mfma_f32_16x16x32_f16(a1, qf1, c, 0, 0, 0);
      S[js] = c;
    }
    // mask -> p = exp2(s) (q carries log2e/8); masked p = 0. No max, no rescale.
    // window test: j in [ig-127, ig+128]  <=>  (unsigned)(j - ig + 127) < 256
    const int relb = j0 - ig + 127 + (quad << 2);
#pragma unroll
    for (int js = 0; js < 4; js++) {
      half4 ph;
#pragma unroll
      for (int r = 0; r < 4; r++) {
        const bool valid = (unsigned)(relb + (js << 4) + r) < 256u;
        const float p = valid ? EXP2F(S[js][r]) : 0.0f;
        l_i += p;
        ph[r] = (_Float16)p;
      }
      *(half4*)&Ps[i_row * 72 + (js << 4) + (quad << 2)] = ph;
    }
    // PV directly: Ps rows are wave-private; same-wave LDS ordering suffices.
    const half8 pa0 = *(const half8*)&Ps[i_row * 72 + (quad << 3)];
    const half8 pa1 = *(const half8*)&Ps[i_row * 72 + 32 + (quad << 3)];
#pragma unroll
    for (int d4 = 0; d4 < 4; d4++) {
      const half8 vb0 = *(const half8*)&Vt[((d4 << 4) + col) * 72 + (quad << 3)];
      const half8 vb1 = *(const half8*)&Vt[((d4 << 4) + col) * 72 + 32 + (quad << 3)];
      accO[d4] = __builtin_amdgcn_mfma_f32_16x16x32_f16(pa0, vb0, accO[d4], 0, 0, 0);
      accO[d4] = __builtin_amdgcn_mfma_f32_16x16x32_f16(pa1, vb1, accO[d4], 0, 0, 0);
    }
  }
  // one cross-lane l reduction for the whole kernel (lanes sharing col = query)
  l_i += __shfl_xor(l_i, 16, 64);
  l_i += __shfl_xor(l_i, 32, 64);
  {
    const float linv = 1.0f / l_i;
    float l4[4];
#pragma unroll
    for (int r = 0; r < 4; r++) l4[r] = __shfl(linv, (quad << 2) + r, 64);
#pragma unroll
    for (int d4 = 0; d4 < 4; d4++)
#pragma unroll
      for (int r = 0; r < 4; r++)
        Osh[((wv << 4) + (quad << 2) + r) * 72 + (d4 << 4) + col] = (_Float16)(accO[d4][r] * l4[r]);
  }
  __syncthreads();
  {
    const int n = nh >> 3, h = nh & 7;
    const int oi = tid >> 2, oc = (tid & 3) << 4;
    _Float16* dst = &ctx[((size_t)n * TSEQ + q0 + oi) * DM + h * HD + oc];
    *(half8*)&dst[0] = *(const half8*)&Osh[oi * 72 + oc];
    *(half8*)&dst[8] = *(const half8*)&Osh[oi * 72 + oc + 8];
  }
}

// ---------------- output projection (f16 MFMA) + bias, f32 out ------------------
// R8 (kept): register prefetch of next K-step's global loads issued before
// compute so HBM/L2 latency hides under fragment reads + MFMA.
__global__ __launch_bounds__(256) void out_gemm_mfma(
    const _Float16* __restrict__ A, const _Float16* __restrict__ B,
    const float* __restrict__ bias, float* __restrict__ out)
{
  __shared__ _Float16 As[128 * 40];
  __shared__ _Float16 Bs[64 * 40];
  const int tid = threadIdx.x;
  const int wv = tid >> 6, lane = tid & 63, quad = lane >> 4, col = lane & 15;
  const int wm = wv >> 1, we = wv & 1;
  const int m0 = blockIdx.x << 7, c0 = blockIdx.y << 6;
  const int sr = tid >> 1, sc = (tid & 1) << 4;
  const int br = tid >> 2, bc = (tid & 3) << 3;
  const _Float16* ap = &A[(size_t)(m0 + sr) * DM + sc];
  const _Float16* bp = &B[(size_t)(c0 + br) * DM + bc];
  floatx4 acc[4][2] = {};
  half8 a0 = *(const half8*)(ap);
  half8 a1 = *(const half8*)(ap + 8);
  half8 b0 = *(const half8*)(bp);
  for (int k0 = 0; k0 < DM; k0 += 32) {
    __syncthreads();
    *(half8*)&As[sr * 40 + sc] = a0;
    *(half8*)&As[sr * 40 + sc + 8] = a1;
    *(half8*)&Bs[br * 40 + bc] = b0;
    half8 an0, an1, bn0;
    const bool more = (k0 + 32 < DM);
    if (more) {
      an0 = *(const half8*)(ap + k0 + 32);
      an1 = *(const half8*)(ap + k0 + 40);
      bn0 = *(const half8*)(bp + k0 + 32);
    }
    __syncthreads();
    half8 af[4], bf[2];
#pragma unroll
    for (int mt = 0; mt < 4; mt++)
      af[mt] = *(const half8*)&As[(wm * 64 + mt * 16 + col) * 40 + quad * 8];
#pragma unroll
    for (int et = 0; et < 2; et++)
      bf[et] = *(const half8*)&Bs[(we * 32 + et * 16 + col) * 40 + quad * 8];
#pragma unroll
    for (int mt = 0; mt < 4; mt++)
#pragma unroll
      for (int et = 0; et < 2; et++)
        acc[mt][et] = __builtin_amdgcn_mfma_f32_16x16x32_f16(af[mt], bf[et], acc[mt][et], 0, 0, 0);
    if (more) { a0 = an0; a1 = an1; b0 = bn0; }
  }
  float bb[2];
#pragma unroll
  for (int et = 0; et < 2; et++) bb[et] = bias[c0 + we * 32 + et * 16 + col];
  const int mbase = m0 + wm * 64 + quad * 4;
#pragma unroll
  for (int mt = 0; mt < 4; mt++)
#pragma unroll
    for (int r = 0; r < 4; r++) {
      const int m = mbase + mt * 16 + r;
#pragma unroll
      for (int et = 0; et < 2; et++)
        out[(size_t)m * DM + c0 + we * 32 + et * 16 + col] = acc[mt][et][r] + bb[et];
    }
}

extern "C" void kernel_launch(void* const* d_in, const int* in_sizes, int n_in,
                              void* d_out, int out_size, void* d_ws, size_t ws_size,
                              hipStream_t stream) {
  const float* x    = (const float*)d_in[0];
  const float* wqkv = (const float*)d_in[1];
  const float* ow   = (const float*)d_in[2];
  const float* ob   = (const float*)d_in[3];
  char* ws = (char*)d_ws;
  _Float16* xh    = (_Float16*)(ws);               //  8,388,608 B
  _Float16* wqkvh = (_Float16*)(ws + 8650752);     //  1,572,864 B
  _Float16* owh   = (_Float16*)(ws + 10485760);    //    524,288 B
  _Float16* qbuf  = (_Float16*)(ws + 11534336);    //  8,388,608 B
  _Float16* kbuf  = (_Float16*)(ws + 20971520);    //  8,388,608 B
  _Float16* vTb   = (_Float16*)(ws + 29360128);    //  8,388,608 B
  _Float16* ctxh  = (_Float16*)(ws + 37748736);    //  8,388,608 B
  float2*   rope  = (float2*)  (ws + 46137344);    //    524,288 B -> end 46,661,632

  prep<<<2688, 256, 0, stream>>>(x, wqkv, ow, ws);        // 688128 16B-units, 1/thread
  qkv_gemm_mfma<<<dim3(64, 12), 256, 0, stream>>>(xh, wqkvh, rope, qbuf, kbuf, vTb);
  attn_win_mfma<<<dim3(32, 32), 256, 0, stream>>>(qbuf, kbuf, vTb, ctxh);
  out_gemm_mfma<<<dim3(64, 8), 256, 0, stream>>>(ctxh, owh, ob, (float*)d_out);
}

// Round 6
// 122.437 us; speedup vs baseline: 1.0437x; 1.0088x over previous
//
#include <hip/hip_runtime.h>
#include <math.h>

#define TSEQ 2048
#define NB 4
#define DM 512
#define NH 8
#define HD 64

typedef _Float16 half8 __attribute__((ext_vector_type(8)));
typedef _Float16 half4 __attribute__((ext_vector_type(4)));
typedef float floatx4 __attribute__((ext_vector_type(4)));

#if __has_builtin(__builtin_amdgcn_exp2f)
#define EXP2F(x) __builtin_amdgcn_exp2f(x)
#else
#define EXP2F(x) exp2f(x)
#endif

// async 16B global->LDS DMA (lane-linear LDS dest: uniform base + lane*16)
__device__ __forceinline__ void gl2lds16(const _Float16* g, _Float16* l) {
  const __attribute__((address_space(1))) unsigned int* gp =
      (const __attribute__((address_space(1))) unsigned int*)(uintptr_t)g;
  __attribute__((address_space(3))) unsigned int* lp =
      (__attribute__((address_space(3))) unsigned int*)(uintptr_t)l;
  __builtin_amdgcn_global_load_lds(gp, lp, 16, 0, 0);
}

// ws layout (bytes):
//   [0,         8388608)  xh      (f16 x)
//   [8650752,  10223616)  wqkvh   (f16 Wqkv)
//   [10485760, 11010048)  owh     (f16 out_w)
//   [11534336, 19922944)  qbuf
//   [20971520, 29360128)  kbuf
//   [29360128, 37748736)  vTb
//   [37748736, 46137344)  ctxh
//   [46137344, 46661632)  rope table (float2 [t][i])

__device__ __forceinline__ void cvt8(const float* __restrict__ src, char* __restrict__ dst,
                                     int unit_src, int unit_dst) {
  const float4 a = ((const float4*)src)[2 * unit_src];
  const float4 b = ((const float4*)src)[2 * unit_src + 1];
  half8 h;
  h[0] = (_Float16)a.x; h[1] = (_Float16)a.y; h[2] = (_Float16)a.z; h[3] = (_Float16)a.w;
  h[4] = (_Float16)b.x; h[5] = (_Float16)b.y; h[6] = (_Float16)b.z; h[7] = (_Float16)b.w;
  *(half8*)(dst + (size_t)unit_dst * 16) = h;
}

// units of 16B: xh 524288 | wqkvh 98304 | owh 32768 | rope 32768  = 688128 total
__global__ void prep(const float* __restrict__ x, const float* __restrict__ wqkv,
                     const float* __restrict__ ow, char* __restrict__ ws) {
  const int i = blockIdx.x * 256 + threadIdx.x;   // grid exactly covers 688128
  if (i < 524288) {                         // xh
    cvt8(x, ws, i, i);
  } else if (i < 622592) {                  // wqkvh
    const int o = i - 524288;
    cvt8(wqkv, ws + 8650752, o, o);
  } else if (i < 655360) {                  // owh
    const int o = i - 622592;
    cvt8(ow, ws + 10485760, o, o);
  } else {                                  // rope table: 2 entries per 16B unit
    const int u = i - 655360;
    float4 o4;
    {
      const int id = 2 * u, t = id >> 5, fi = id & 31;
      const float invf = powf(10000.0f, -(float)(2 * fi) * (1.0f / 64.0f));
      float s, c; sincosf((float)t * invf, &s, &c);
      o4.x = c; o4.y = s;
    }
    {
      const int id = 2 * u + 1, t = id >> 5, fi = id & 31;
      const float invf = powf(10000.0f, -(float)(2 * fi) * (1.0f / 64.0f));
      float s, c; sincosf((float)t * invf, &s, &c);
      o4.z = c; o4.w = s;
    }
    ((float4*)(ws + 46137344))[u] = o4;
  }
}

// ---------------- QKV GEMM (f16 MFMA) + fused RoPE -----------------------------
// R8 (kept): double-buffered LDS pipeline; stage of tile k+1 issued before the
// compute of tile k; one barrier per 32-K-step.
__global__ __launch_bounds__(256) void qkv_gemm_mfma(
    const _Float16* __restrict__ A, const _Float16* __restrict__ B,
    const float2* __restrict__ rope,
    _Float16* __restrict__ qb, _Float16* __restrict__ kb, _Float16* __restrict__ vT)
{
  __shared__ __align__(16) _Float16 As0[128 * 32];
  __shared__ __align__(16) _Float16 Bs0[128 * 32];
  __shared__ __align__(16) _Float16 As1[128 * 32];
  __shared__ __align__(16) _Float16 Bs1[128 * 32];
  const int tid = threadIdx.x;
  const int wv = tid >> 6, lane = tid & 63, quad = lane >> 4, col = lane & 15;
  const int wm = wv >> 1, we = wv & 1;
  const int m0 = blockIdx.x << 7, c0 = blockIdx.y << 7;
  const int r0 = tid >> 2, p0 = tid & 3;
  const int cA0 = (p0 - (r0 >> 1)) & 3;
  const int r1 = (tid + 256) >> 2, p1 = tid & 3;
  const int cA1 = (p1 - (r1 >> 1)) & 3;
  const _Float16* ga0 = &A[(size_t)(m0 + r0) * DM + cA0 * 8];
  const _Float16* ga1 = &A[(size_t)(m0 + r1) * DM + cA1 * 8];
  const _Float16* gb0 = &B[(size_t)(c0 + r0) * DM + cA0 * 8];
  const _Float16* gb1 = &B[(size_t)(c0 + r1) * DM + cA1 * 8];
  floatx4 acc[4][4] = {};   // [mt][et]

#define QKV_STAGE(AS, BS, K)                      \
  do {                                            \
    gl2lds16(ga0 + (K), &AS[tid * 8]);            \
    gl2lds16(ga1 + (K), &AS[(tid + 256) * 8]);    \
    gl2lds16(gb0 + (K), &BS[tid * 8]);            \
    gl2lds16(gb1 + (K), &BS[(tid + 256) * 8]);    \
  } while (0)

#define QKV_COMPUTE(AS, BS)                                                   \
  do {                                                                        \
    half8 af[4], bf[4];                                                       \
    _Pragma("unroll") for (int mt = 0; mt < 4; mt++) {                        \
      const int R = wm * 64 + mt * 16 + col;                                  \
      af[mt] = *(const half8*)&AS[R * 32 + (((quad + (R >> 1)) & 3) << 3)];   \
    }                                                                         \
    _Pragma("unroll") for (int et = 0; et < 4; et++) {                        \
      const int R = we * 64 + et * 16 + col;                                  \
      bf[et] = *(const half8*)&BS[R * 32 + (((quad + (R >> 1)) & 3) << 3)];   \
    }                                                                         \
    _Pragma("unroll") for (int mt = 0; mt < 4; mt++)                          \
      _Pragma("unroll") for (int et = 0; et < 4; et++)                        \
        acc[mt][et] =                                                         \
            __builtin_amdgcn_mfma_f32_16x16x32_f16(af[mt], bf[et], acc[mt][et], 0, 0, 0); \
  } while (0)

  QKV_STAGE(As0, Bs0, 0);       // prologue: tile 0 in flight
  for (int k0 = 0; k0 < DM; k0 += 64) {
    __syncthreads();                    // buf0(k0) landed & visible; prev reads done
    QKV_STAGE(As1, Bs1, k0 + 32);       // next tile flies under compute below
    QKV_COMPUTE(As0, Bs0);
    __syncthreads();                    // buf1 landed & visible; buf0 reads done
    if (k0 + 64 < DM) QKV_STAGE(As0, Bs0, k0 + 64);
    QKV_COMPUTE(As1, Bs1);
  }
#undef QKV_STAGE
#undef QKV_COMPUTE

  const int eidx = (c0 >> 6) + we;            // 0..23, wave-uniform
  const int three = eidx >> 3, h = eidx & 7;
  const int mbase = m0 + wm * 64 + quad * 4;
  if (three == 2) {
#pragma unroll
    for (int mt = 0; mt < 4; mt++) {
      const int m = mbase + mt * 16;
      const int n = m >> 11, t = m & 2047;
#pragma unroll
      for (int et = 0; et < 4; et++) {
        const int dh = et * 16 + col;
        half4 hv;
#pragma unroll
        for (int r = 0; r < 4; r++) hv[r] = (_Float16)acc[mt][et][r];
        *(half4*)&vT[(size_t)(n * NH + h) * HD * TSEQ + (size_t)dh * TSEQ + t] = hv;
      }
    }
  } else {
    _Float16* dst = three ? kb : qb;
    // q scale = (1/8) * log2(e) so attention's exp is a bare v_exp_f32
    const float scl = three ? 1.0f : 0.125f * 1.4426950408889634f;
#pragma unroll
    for (int mt = 0; mt < 4; mt++)
#pragma unroll
      for (int r = 0; r < 4; r++) {
        const int m = mbase + mt * 16 + r;
        const int n = m >> 11, t = m & 2047;
#pragma unroll
        for (int et = 0; et < 4; et++) {
          const int i = ((et & 1) << 4) + col;
          const float2 cs = rope[t * 32 + i];
          const float v = acc[mt][et][r];
          const float v2 = acc[mt][et ^ 2][r];
          const float o = (et < 2) ? (v * cs.x - v2 * cs.y) : (v * cs.x + v2 * cs.y);
          dst[((size_t)(n * NH + h) * TSEQ + t) * HD + et * 16 + col] = (_Float16)(o * scl);
        }
      }
  }
}

// ---------------- windowed flash attention, shift-free softmax ----------------
// R5/R10 structure (2 barriers/tile, reg prefetch, XCD swizzle) + R11: wave-
// uniform skip of fully-masked 16-wide j-subtiles. A wave's 16 queries span a
// 271-wide valid window but the 5 k-tiles cover 320 columns; ~3 of 20 subtiles
// per wave are entirely out-of-window. Condition depends only on (q0,wv,j0,js)
// -> s_cbranch, no divergence. Skipped: 2 MFMA + 2 ds_read_b128 + 4 exp;
// Ps rows still get zeros so PV is unchanged.
__global__ __launch_bounds__(256, 4) void attn_win_mfma(
    const _Float16* __restrict__ qb, const _Float16* __restrict__ kb,
    const _Float16* __restrict__ vT, _Float16* __restrict__ ctx)
{
  __shared__ __align__(16) char smem[36864];
  _Float16* Ks = (_Float16*)smem;              // [64][72] j-major
  _Float16* Vt = (_Float16*)(smem + 9216);     // [64][72] d-major (from vT global)
  _Float16* Ps = (_Float16*)(smem + 18432);    // [64][72] i-major (wave-private rows)
  _Float16* Osh = (_Float16*)(smem + 27648);   // [64][72] dedicated

  const int tid = threadIdx.x;
  const int wv = tid >> 6;
  const int lane = tid & 63;
  const int quad = lane >> 4;
  const int col = lane & 15;
  // XCD swizzle: lin%8 = XCD -> give each XCD a contiguous 128-block chunk
  const int lin = (blockIdx.y << 5) | blockIdx.x;
  const int sl  = ((lin & 7) << 7) | (lin >> 3);
  const int nh = sl >> 5;
  const int q0 = (sl & 31) << 6;
  const _Float16* qp = qb + (size_t)nh * TSEQ * HD;
  const _Float16* kp = kb + (size_t)nh * TSEQ * HD;
  const _Float16* vp = vT + (size_t)nh * HD * TSEQ;

  const int i_row = (wv << 4) + col;
  const int ig = q0 + i_row;
  const half8 qf0 = *(const half8*)&qp[(size_t)ig * HD + (quad << 3)];
  const half8 qf1 = *(const half8*)&qp[(size_t)ig * HD + 32 + (quad << 3)];

  float l_i = 0.0f;          // per-lane partial sum of p
  floatx4 accO[4] = {};

  const int kt0 = max(0, q0 - 127) >> 6;
  const int kt1 = min(TSEQ - 1, q0 + 191) >> 6;
  const int kr = tid >> 2, kc = (tid & 3) << 4;    // K: row j, col d
  const int vd = tid >> 2, vc = (tid & 3) << 4;    // V^T: row d, col j
  const _Float16* kpr = kp + (size_t)kr * HD + kc; // + j0*HD selects the tile
  const _Float16* vpr = vp + (size_t)vd * TSEQ + vc; // + j0 selects the tile
  const int iw0 = q0 + (wv << 4);                  // wave's first query

  // prologue: load first tile into registers
  half8 ck0 = *(const half8*)(kpr + (size_t)(kt0 << 6) * HD);
  half8 ck1 = *(const half8*)(kpr + (size_t)(kt0 << 6) * HD + 8);
  half8 cv0 = *(const half8*)(vpr + (kt0 << 6));
  half8 cv1 = *(const half8*)(vpr + (kt0 << 6) + 8);

  for (int kt = kt0; kt <= kt1; kt++) {
    const int j0 = kt << 6;
    __syncthreads();   // previous iteration's LDS reads complete
    *(half8*)&Ks[kr * 72 + kc] = ck0;
    *(half8*)&Ks[kr * 72 + kc + 8] = ck1;
    *(half8*)&Vt[vd * 72 + vc] = cv0;
    *(half8*)&Vt[vd * 72 + vc + 8] = cv1;
    __syncthreads();   // staging visible

    // prefetch NEXT tile into registers; latency hides under compute below.
    {
      const int jn = (kt < kt1) ? (j0 + 64) : j0;
      ck0 = *(const half8*)(kpr + (size_t)jn * HD);
      ck1 = *(const half8*)(kpr + (size_t)jn * HD + 8);
      cv0 = *(const half8*)(vpr + jn);
      cv1 = *(const half8*)(vpr + jn + 8);
    }

    // live(js): subtile [jlo, jlo+15] intersects wave window [iw0-127, iw0+143]
    // <=> jlo in [iw0-142, iw0+143] <=> (unsigned)(jlo - iw0 + 142) < 286
    // S^T[j][i]: A = K rows, B = Q^T. C-layout: row=j_local, col=i(=our query)
    floatx4 S[4];
#pragma unroll
    for (int js = 0; js < 4; js++) {
      const int jlo = j0 + (js << 4);
      if ((unsigned)(jlo - iw0 + 142) < 286u) {
        const half8 a0 = *(const half8*)&Ks[((js << 4) + col) * 72 + (quad << 3)];
        const half8 a1 = *(const half8*)&Ks[((js << 4) + col) * 72 + 32 + (quad << 3)];
        floatx4 c = {0.f, 0.f, 0.f, 0.f};
        c = __builtin_amdgcn_mfma_f32_16x16x32_f16(a0, qf0, c, 0, 0, 0);
        c = __builtin_amdgcn_mfma_f32_16x16x32_f16(a1, qf1, c, 0, 0, 0);
        S[js] = c;
      }
    }
    // mask -> p = exp2(s) (q carries log2e/8); masked p = 0. No max, no rescale.
    // window test: j in [ig-127, ig+128]  <=>  (unsigned)(j - ig + 127) < 256
    const int relb = j0 - ig + 127 + (quad << 2);
#pragma unroll
    for (int js = 0; js < 4; js++) {
      const int jlo = j0 + (js << 4);
      if ((unsigned)(jlo - iw0 + 142) < 286u) {
        half4 ph;
#pragma unroll
        for (int r = 0; r < 4; r++) {
          const bool valid = (unsigned)(relb + (js << 4) + r) < 256u;
          const float p = valid ? EXP2F(S[js][r]) : 0.0f;
          l_i += p;
          ph[r] = (_Float16)p;
        }
        *(half4*)&Ps[i_row * 72 + (js << 4) + (quad << 2)] = ph;
      } else {
        const half4 zz = {(_Float16)0.f, (_Float16)0.f, (_Float16)0.f, (_Float16)0.f};
        *(half4*)&Ps[i_row * 72 + (js << 4) + (quad << 2)] = zz;
      }
    }
    // PV directly: Ps rows are wave-private; same-wave LDS ordering suffices.
    const half8 pa0 = *(const half8*)&Ps[i_row * 72 + (quad << 3)];
    const half8 pa1 = *(const half8*)&Ps[i_row * 72 + 32 + (quad << 3)];
#pragma unroll
    for (int d4 = 0; d4 < 4; d4++) {
      const half8 vb0 = *(const half8*)&Vt[((d4 << 4) + col) * 72 + (quad << 3)];
      const half8 vb1 = *(const half8*)&Vt[((d4 << 4) + col) * 72 + 32 + (quad << 3)];
      accO[d4] = __builtin_amdgcn_mfma_f32_16x16x32_f16(pa0, vb0, accO[d4], 0, 0, 0);
      accO[d4] = __builtin_amdgcn_mfma_f32_16x16x32_f16(pa1, vb1, accO[d4], 0, 0, 0);
    }
  }
  // one cross-lane l reduction for the whole kernel (lanes sharing col = query)
  l_i += __shfl_xor(l_i, 16, 64);
  l_i += __shfl_xor(l_i, 32, 64);
  {
    const float linv = 1.0f / l_i;
    float l4[4];
#pragma unroll
    for (int r = 0; r < 4; r++) l4[r] = __shfl(linv, (quad << 2) + r, 64);
#pragma unroll
    for (int d4 = 0; d4 < 4; d4++)
#pragma unroll
      for (int r = 0; r < 4; r++)
        Osh[((wv << 4) + (quad << 2) + r) * 72 + (d4 << 4) + col] = (_Float16)(accO[d4][r] * l4[r]);
  }
  __syncthreads();
  {
    const int n = nh >> 3, h = nh & 7;
    const int oi = tid >> 2, oc = (tid & 3) << 4;
    _Float16* dst = &ctx[((size_t)n * TSEQ + q0 + oi) * DM + h * HD + oc];
    *(half8*)&dst[0] = *(const half8*)&Osh[oi * 72 + oc];
    *(half8*)&dst[8] = *(const half8*)&Osh[oi * 72 + oc + 8];
  }
}

// ---------------- output projection (f16 MFMA) + bias, f32 out ------------------
// R11: qkv-style global_load_lds double-buffered pipeline (was reg-staged with
// 2 barriers per 32-K-step). A tile 128x32 identical to qkv; B tile 64x32 is
// exactly one 256-thread DMA round. Barriers 32 -> 16; staging latency hides
// under a full compute phase.
__global__ __launch_bounds__(256) void out_gemm_mfma(
    const _Float16* __restrict__ A, const _Float16* __restrict__ B,
    const float* __restrict__ bias, float* __restrict__ out)
{
  __shared__ __align__(16) _Float16 As0[128 * 32];
  __shared__ __align__(16) _Float16 Bs0[64 * 32];
  __shared__ __align__(16) _Float16 As1[128 * 32];
  __shared__ __align__(16) _Float16 Bs1[64 * 32];
  const int tid = threadIdx.x;
  const int wv = tid >> 6, lane = tid & 63, quad = lane >> 4, col = lane & 15;
  const int wm = wv >> 1, we = wv & 1;
  const int m0 = blockIdx.x << 7, c0 = blockIdx.y << 6;
  const int r0 = tid >> 2, p0 = tid & 3;
  const int cA0 = (p0 - (r0 >> 1)) & 3;
  const int r1 = (tid + 256) >> 2;
  const int cA1 = (p0 - (r1 >> 1)) & 3;
  const _Float16* ga0 = &A[(size_t)(m0 + r0) * DM + cA0 * 8];
  const _Float16* ga1 = &A[(size_t)(m0 + r1) * DM + cA1 * 8];
  const _Float16* gb0 = &B[(size_t)(c0 + r0) * DM + cA0 * 8];   // 64 rows, 4 phases
  floatx4 acc[4][2] = {};

#define OG_STAGE(AS, BS, K)                       \
  do {                                            \
    gl2lds16(ga0 + (K), &AS[tid * 8]);            \
    gl2lds16(ga1 + (K), &AS[(tid + 256) * 8]);    \
    gl2lds16(gb0 + (K), &BS[tid * 8]);            \
  } while (0)

#define OG_COMPUTE(AS, BS)                                                    \
  do {                                                                        \
    half8 af[4], bf[2];                                                       \
    _Pragma("unroll") for (int mt = 0; mt < 4; mt++) {                        \
      const int R = wm * 64 + mt * 16 + col;                                  \
      af[mt] = *(const half8*)&AS[R * 32 + (((quad + (R >> 1)) & 3) << 3)];   \
    }                                                                         \
    _Pragma("unroll") for (int et = 0; et < 2; et++) {                        \
      const int R = we * 32 + et * 16 + col;                                  \
      bf[et] = *(const half8*)&BS[R * 32 + (((quad + (R >> 1)) & 3) << 3)];   \
    }                                                                         \
    _Pragma("unroll") for (int mt = 0; mt < 4; mt++)                          \
      _Pragma("unroll") for (int et = 0; et < 2; et++)                        \
        acc[mt][et] =                                                         \
            __builtin_amdgcn_mfma_f32_16x16x32_f16(af[mt], bf[et], acc[mt][et], 0, 0, 0); \
  } while (0)

  OG_STAGE(As0, Bs0, 0);
  for (int k0 = 0; k0 < DM; k0 += 64) {
    __syncthreads();                    // buf0(k0) landed & visible; prev reads done
    OG_STAGE(As1, Bs1, k0 + 32);
    OG_COMPUTE(As0, Bs0);
    __syncthreads();
    if (k0 + 64 < DM) OG_STAGE(As0, Bs0, k0 + 64);
    OG_COMPUTE(As1, Bs1);
  }
#undef OG_STAGE
#undef OG_COMPUTE

  float bb[2];
#pragma unroll
  for (int et = 0; et < 2; et++) bb[et] = bias[c0 + we * 32 + et * 16 + col];
  const int mbase = m0 + wm * 64 + quad * 4;
#pragma unroll
  for (int mt = 0; mt < 4; mt++)
#pragma unroll
    for (int r = 0; r < 4; r++) {
      const int m = mbase + mt * 16 + r;
#pragma unroll
      for (int et = 0; et < 2; et++)
        out[(size_t)m * DM + c0 + we * 32 + et * 16 + col] = acc[mt][et][r] + bb[et];
    }
}

extern "C" void kernel_launch(void* const* d_in, const int* in_sizes, int n_in,
                              void* d_out, int out_size, void* d_ws, size_t ws_size,
                              hipStream_t stream) {
  const float* x    = (const float*)d_in[0];
  const float* wqkv = (const float*)d_in[1];
  const float* ow   = (const float*)d_in[2];
  const float* ob   = (const float*)d_in[3];
  char* ws = (char*)d_ws;
  _Float16* xh    = (_Float16*)(ws);               //  8,388,608 B
  _Float16* wqkvh = (_Float16*)(ws + 8650752);     //  1,572,864 B
  _Float16* owh   = (_Float16*)(ws + 10485760);    //    524,288 B
  _Float16* qbuf  = (_Float16*)(ws + 11534336);    //  8,388,608 B
  _Float16* kbuf  = (_Float16*)(ws + 20971520);    //  8,388,608 B
  _Float16* vTb   = (_Float16*)(ws + 29360128);    //  8,388,608 B
  _Float16* ctxh  = (_Float16*)(ws + 37748736);    //  8,388,608 B
  float2*   rope  = (float2*)  (ws + 46137344);    //    524,288 B -> end 46,661,632

  prep<<<2688, 256, 0, stream>>>(x, wqkv, ow, ws);        // 688128 16B-units, 1/thread
  qkv_gemm_mfma<<<dim3(64, 12), 256, 0, stream>>>(xh, wqkvh, rope, qbuf, kbuf, vTb);
  attn_win_mfma<<<dim3(32, 32), 256, 0, stream>>>(qbuf, kbuf, vTb, ctxh);
  out_gemm_mfma<<<dim3(64, 8), 256, 0, stream>>>(ctxh, owh, ob, (float*)d_out);
}

// Round 7
// 121.803 us; speedup vs baseline: 1.0491x; 1.0052x over previous
//
#include <hip/hip_runtime.h>
#include <math.h>

#define TSEQ 2048
#define NB 4
#define DM 512
#define NH 8
#define HD 64

typedef _Float16 half8 __attribute__((ext_vector_type(8)));
typedef _Float16 half4 __attribute__((ext_vector_type(4)));
typedef float floatx4 __attribute__((ext_vector_type(4)));

#if __has_builtin(__builtin_amdgcn_exp2f)
#define EXP2F(x) __builtin_amdgcn_exp2f(x)
#else
#define EXP2F(x) exp2f(x)
#endif

// async 16B global->LDS DMA (lane-linear LDS dest: uniform base + lane*16)
__device__ __forceinline__ void gl2lds16(const _Float16* g, _Float16* l) {
  const __attribute__((address_space(1))) unsigned int* gp =
      (const __attribute__((address_space(1))) unsigned int*)(uintptr_t)g;
  __attribute__((address_space(3))) unsigned int* lp =
      (__attribute__((address_space(3))) unsigned int*)(uintptr_t)l;
  __builtin_amdgcn_global_load_lds(gp, lp, 16, 0, 0);
}

// ws layout (bytes):
//   [0,         8388608)  xh      (f16 x)
//   [8650752,  10223616)  wqkvh   (f16 Wqkv)
//   [10485760, 11010048)  owh     (f16 out_w)
//   [11534336, 19922944)  qbuf
//   [20971520, 29360128)  kbuf
//   [29360128, 37748736)  vTb
//   [37748736, 46137344)  ctxh
//   [46137344, 46661632)  rope table (float2 [t][i])

__device__ __forceinline__ void cvt8(const float* __restrict__ src, char* __restrict__ dst,
                                     int unit_src, int unit_dst) {
  const float4 a = ((const float4*)src)[2 * unit_src];
  const float4 b = ((const float4*)src)[2 * unit_src + 1];
  half8 h;
  h[0] = (_Float16)a.x; h[1] = (_Float16)a.y; h[2] = (_Float16)a.z; h[3] = (_Float16)a.w;
  h[4] = (_Float16)b.x; h[5] = (_Float16)b.y; h[6] = (_Float16)b.z; h[7] = (_Float16)b.w;
  *(half8*)(dst + (size_t)unit_dst * 16) = h;
}

// units of 16B: xh 524288 | wqkvh 98304 | owh 32768 | rope 32768  = 688128 total
__global__ void prep(const float* __restrict__ x, const float* __restrict__ wqkv,
                     const float* __restrict__ ow, char* __restrict__ ws) {
  const int i = blockIdx.x * 256 + threadIdx.x;   // grid exactly covers 688128
  if (i < 524288) {                         // xh
    cvt8(x, ws, i, i);
  } else if (i < 622592) {                  // wqkvh
    const int o = i - 524288;
    cvt8(wqkv, ws + 8650752, o, o);
  } else if (i < 655360) {                  // owh
    const int o = i - 622592;
    cvt8(ow, ws + 10485760, o, o);
  } else {                                  // rope table: 2 entries per 16B unit
    const int u = i - 655360;
    float4 o4;
    {
      const int id = 2 * u, t = id >> 5, fi = id & 31;
      const float invf = powf(10000.0f, -(float)(2 * fi) * (1.0f / 64.0f));
      float s, c; sincosf((float)t * invf, &s, &c);
      o4.x = c; o4.y = s;
    }
    {
      const int id = 2 * u + 1, t = id >> 5, fi = id & 31;
      const float invf = powf(10000.0f, -(float)(2 * fi) * (1.0f / 64.0f));
      float s, c; sincosf((float)t * invf, &s, &c);
      o4.z = c; o4.w = s;
    }
    ((float4*)(ws + 46137344))[u] = o4;
  }
}

// ---------------- QKV GEMM (f16 MFMA) + fused RoPE -----------------------------
// R8 (kept): double-buffered LDS pipeline; stage of tile k+1 issued before the
// compute of tile k; one barrier per 32-K-step.
__global__ __launch_bounds__(256) void qkv_gemm_mfma(
    const _Float16* __restrict__ A, const _Float16* __restrict__ B,
    const float2* __restrict__ rope,
    _Float16* __restrict__ qb, _Float16* __restrict__ kb, _Float16* __restrict__ vT)
{
  __shared__ __align__(16) _Float16 As0[128 * 32];
  __shared__ __align__(16) _Float16 Bs0[128 * 32];
  __shared__ __align__(16) _Float16 As1[128 * 32];
  __shared__ __align__(16) _Float16 Bs1[128 * 32];
  const int tid = threadIdx.x;
  const int wv = tid >> 6, lane = tid & 63, quad = lane >> 4, col = lane & 15;
  const int wm = wv >> 1, we = wv & 1;
  const int m0 = blockIdx.x << 7, c0 = blockIdx.y << 7;
  const int r0 = tid >> 2, p0 = tid & 3;
  const int cA0 = (p0 - (r0 >> 1)) & 3;
  const int r1 = (tid + 256) >> 2, p1 = tid & 3;
  const int cA1 = (p1 - (r1 >> 1)) & 3;
  const _Float16* ga0 = &A[(size_t)(m0 + r0) * DM + cA0 * 8];
  const _Float16* ga1 = &A[(size_t)(m0 + r1) * DM + cA1 * 8];
  const _Float16* gb0 = &B[(size_t)(c0 + r0) * DM + cA0 * 8];
  const _Float16* gb1 = &B[(size_t)(c0 + r1) * DM + cA1 * 8];
  floatx4 acc[4][4] = {};   // [mt][et]

#define QKV_STAGE(AS, BS, K)                      \
  do {                                            \
    gl2lds16(ga0 + (K), &AS[tid * 8]);            \
    gl2lds16(ga1 + (K), &AS[(tid + 256) * 8]);    \
    gl2lds16(gb0 + (K), &BS[tid * 8]);            \
    gl2lds16(gb1 + (K), &BS[(tid + 256) * 8]);    \
  } while (0)

#define QKV_COMPUTE(AS, BS)                                                   \
  do {                                                                        \
    half8 af[4], bf[4];                                                       \
    _Pragma("unroll") for (int mt = 0; mt < 4; mt++) {                        \
      const int R = wm * 64 + mt * 16 + col;                                  \
      af[mt] = *(const half8*)&AS[R * 32 + (((quad + (R >> 1)) & 3) << 3)];   \
    }                                                                         \
    _Pragma("unroll") for (int et = 0; et < 4; et++) {                        \
      const int R = we * 64 + et * 16 + col;                                  \
      bf[et] = *(const half8*)&BS[R * 32 + (((quad + (R >> 1)) & 3) << 3)];   \
    }                                                                         \
    _Pragma("unroll") for (int mt = 0; mt < 4; mt++)                          \
      _Pragma("unroll") for (int et = 0; et < 4; et++)                        \
        acc[mt][et] =                                                         \
            __builtin_amdgcn_mfma_f32_16x16x32_f16(af[mt], bf[et], acc[mt][et], 0, 0, 0); \
  } while (0)

  QKV_STAGE(As0, Bs0, 0);       // prologue: tile 0 in flight
  for (int k0 = 0; k0 < DM; k0 += 64) {
    __syncthreads();                    // buf0(k0) landed & visible; prev reads done
    QKV_STAGE(As1, Bs1, k0 + 32);       // next tile flies under compute below
    QKV_COMPUTE(As0, Bs0);
    __syncthreads();                    // buf1 landed & visible; buf0 reads done
    if (k0 + 64 < DM) QKV_STAGE(As0, Bs0, k0 + 64);
    QKV_COMPUTE(As1, Bs1);
  }
#undef QKV_STAGE
#undef QKV_COMPUTE

  const int eidx = (c0 >> 6) + we;            // 0..23, wave-uniform
  const int three = eidx >> 3, h = eidx & 7;
  const int mbase = m0 + wm * 64 + quad * 4;
  if (three == 2) {
#pragma unroll
    for (int mt = 0; mt < 4; mt++) {
      const int m = mbase + mt * 16;
      const int n = m >> 11, t = m & 2047;
#pragma unroll
      for (int et = 0; et < 4; et++) {
        const int dh = et * 16 + col;
        half4 hv;
#pragma unroll
        for (int r = 0; r < 4; r++) hv[r] = (_Float16)acc[mt][et][r];
        *(half4*)&vT[(size_t)(n * NH + h) * HD * TSEQ + (size_t)dh * TSEQ + t] = hv;
      }
    }
  } else {
    _Float16* dst = three ? kb : qb;
    // q scale = (1/8) * log2(e) so attention's exp is a bare v_exp_f32
    const float scl = three ? 1.0f : 0.125f * 1.4426950408889634f;
#pragma unroll
    for (int mt = 0; mt < 4; mt++)
#pragma unroll
      for (int r = 0; r < 4; r++) {
        const int m = mbase + mt * 16 + r;
        const int n = m >> 11, t = m & 2047;
#pragma unroll
        for (int et = 0; et < 4; et++) {
          const int i = ((et & 1) << 4) + col;
          const float2 cs = rope[t * 32 + i];
          const float v = acc[mt][et][r];
          const float v2 = acc[mt][et ^ 2][r];
          const float o = (et < 2) ? (v * cs.x - v2 * cs.y) : (v * cs.x + v2 * cs.y);
          dst[((size_t)(n * NH + h) * TSEQ + t) * HD + et * 16 + col] = (_Float16)(o * scl);
        }
      }
  }
}

// ---------------- windowed flash attention, shift-free softmax ----------------
// R12: QBLK=128 (8 waves, 512 threads). A 128-query block spans a 383-wide
// j-window -> 6 staged tiles per 128 queries (was 2 blocks x 5 = 10): K/V
// staging traffic, global K/V re-reads, and barrier count drop ~40%/query.
// Per-wave useful work unchanged (271-window, subtile skip kept); NEW wave-
// uniform whole-tile skip drops QK+exp+Ps+PV for tiles fully outside the
// wave's window (each wave has >=1 such tile; barriers still uniform).
// LDS 54KB -> 2 blocks/CU x 8 waves = 16 waves/CU (same as R6). XCD swizzle:
// 512 blocks, 64 contiguous per XCD = 4 complete batch-heads (~2MB K/V, L2-fit).
__global__ __launch_bounds__(512, 4) void attn_win_mfma(
    const _Float16* __restrict__ qb, const _Float16* __restrict__ kb,
    const _Float16* __restrict__ vT, _Float16* __restrict__ ctx)
{
  __shared__ __align__(16) char smem[55296];
  _Float16* Ks = (_Float16*)smem;              // [64][72] j-major
  _Float16* Vt = (_Float16*)(smem + 9216);     // [64][72] d-major (from vT global)
  _Float16* Ps = (_Float16*)(smem + 18432);    // [128][72] i-major (wave-private rows)
  _Float16* Osh = (_Float16*)(smem + 36864);   // [128][72]

  const int tid = threadIdx.x;
  const int wv = tid >> 6;                     // 0..7
  const int lane = tid & 63;
  const int quad = lane >> 4;
  const int col = lane & 15;
  // XCD swizzle: lin%8 = XCD -> 64 contiguous sl per XCD = 4 batch-heads
  const int lin = (blockIdx.y << 4) | blockIdx.x;          // 0..511
  const int sl  = ((lin & 7) << 6) | (lin >> 3);
  const int nh = sl >> 4;
  const int q0 = (sl & 15) << 7;
  const _Float16* qp = qb + (size_t)nh * TSEQ * HD;
  const _Float16* kp = kb + (size_t)nh * TSEQ * HD;
  const _Float16* vp = vT + (size_t)nh * HD * TSEQ;

  const int i_row = (wv << 4) + col;           // 0..127
  const int ig = q0 + i_row;
  const half8 qf0 = *(const half8*)&qp[(size_t)ig * HD + (quad << 3)];
  const half8 qf1 = *(const half8*)&qp[(size_t)ig * HD + 32 + (quad << 3)];

  float l_i = 0.0f;          // per-lane partial sum of p
  floatx4 accO[4] = {};

  const int kt0 = max(0, q0 - 127) >> 6;
  const int kt1 = min(TSEQ - 1, q0 + 255) >> 6;
  // staging: 512 threads cover one 64x64 f16 tile at 16B/thread
  const int kr = tid >> 3, kc = (tid & 7) << 3;      // row 0..63, col-chunk 0..56
  const _Float16* kpr = kp + (size_t)kr * HD + kc;   // + j0*HD selects K tile
  const _Float16* vpr = vp + (size_t)kr * TSEQ + kc; // + j0 selects V^T tile
  const int iw0 = q0 + (wv << 4);                    // wave's first query

  // prologue: load first tile into registers
  half8 ck = *(const half8*)(kpr + (size_t)(kt0 << 6) * HD);
  half8 cv = *(const half8*)(vpr + (kt0 << 6));

  for (int kt = kt0; kt <= kt1; kt++) {
    const int j0 = kt << 6;
    __syncthreads();   // previous iteration's LDS reads complete
    *(half8*)&Ks[kr * 72 + kc] = ck;
    *(half8*)&Vt[kr * 72 + kc] = cv;
    __syncthreads();   // staging visible

    // prefetch NEXT tile into registers; latency hides under compute below.
    {
      const int jn = (kt < kt1) ? (j0 + 64) : j0;
      ck = *(const half8*)(kpr + (size_t)jn * HD);
      cv = *(const half8*)(vpr + jn);
    }

    // wave-uniform whole-tile skip: tile [j0, j0+63] intersects wave window
    // [iw0-127, iw0+143] iff j0 in [iw0-190, iw0+143]
    if ((unsigned)(j0 - iw0 + 190) >= 334u) continue;

    // live(js): subtile [jlo, jlo+15] intersects [iw0-127, iw0+143]
    // <=> (unsigned)(jlo - iw0 + 142) < 286
    // S^T[j][i]: A = K rows, B = Q^T. C-layout: row=j_local, col=i(=our query)
    floatx4 S[4];
#pragma unroll
    for (int js = 0; js < 4; js++) {
      const int jlo = j0 + (js << 4);
      if ((unsigned)(jlo - iw0 + 142) < 286u) {
        const half8 a0 = *(const half8*)&Ks[((js << 4) + col) * 72 + (quad << 3)];
        const half8 a1 = *(const half8*)&Ks[((js << 4) + col) * 72 + 32 + (quad << 3)];
        floatx4 c = {0.f, 0.f, 0.f, 0.f};
        c = __builtin_amdgcn_mfma_f32_16x16x32_f16(a0, qf0, c, 0, 0, 0);
        c = __builtin_amdgcn_mfma_f32_16x16x32_f16(a1, qf1, c, 0, 0, 0);
        S[js] = c;
      }
    }
    // mask -> p = exp2(s) (q carries log2e/8); masked p = 0. No max, no rescale.
    // window test: j in [ig-127, ig+128]  <=>  (unsigned)(j - ig + 127) < 256
    const int relb = j0 - ig + 127 + (quad << 2);
#pragma unroll
    for (int js = 0; js < 4; js++) {
      const int jlo = j0 + (js << 4);
      if ((unsigned)(jlo - iw0 + 142) < 286u) {
        half4 ph;
#pragma unroll
        for (int r = 0; r < 4; r++) {
          const bool valid = (unsigned)(relb + (js << 4) + r) < 256u;
          const float p = valid ? EXP2F(S[js][r]) : 0.0f;
          l_i += p;
          ph[r] = (_Float16)p;
        }
        *(half4*)&Ps[i_row * 72 + (js << 4) + (quad << 2)] = ph;
      } else {
        const half4 zz = {(_Float16)0.f, (_Float16)0.f, (_Float16)0.f, (_Float16)0.f};
        *(half4*)&Ps[i_row * 72 + (js << 4) + (quad << 2)] = zz;
      }
    }
    // PV directly: Ps rows are wave-private; same-wave LDS ordering suffices.
    const half8 pa0 = *(const half8*)&Ps[i_row * 72 + (quad << 3)];
    const half8 pa1 = *(const half8*)&Ps[i_row * 72 + 32 + (quad << 3)];
#pragma unroll
    for (int d4 = 0; d4 < 4; d4++) {
      const half8 vb0 = *(const half8*)&Vt[((d4 << 4) + col) * 72 + (quad << 3)];
      const half8 vb1 = *(const half8*)&Vt[((d4 << 4) + col) * 72 + 32 + (quad << 3)];
      accO[d4] = __builtin_amdgcn_mfma_f32_16x16x32_f16(pa0, vb0, accO[d4], 0, 0, 0);
      accO[d4] = __builtin_amdgcn_mfma_f32_16x16x32_f16(pa1, vb1, accO[d4], 0, 0, 0);
    }
  }
  // one cross-lane l reduction for the whole kernel (lanes sharing col = query)
  l_i += __shfl_xor(l_i, 16, 64);
  l_i += __shfl_xor(l_i, 32, 64);
  {
    const float linv = 1.0f / l_i;
    float l4[4];
#pragma unroll
    for (int r = 0; r < 4; r++) l4[r] = __shfl(linv, (quad << 2) + r, 64);
#pragma unroll
    for (int d4 = 0; d4 < 4; d4++)
#pragma unroll
      for (int r = 0; r < 4; r++)
        Osh[((wv << 4) + (quad << 2) + r) * 72 + (d4 << 4) + col] = (_Float16)(accO[d4][r] * l4[r]);
  }
  __syncthreads();
  {
    const int n = nh >> 3, h = nh & 7;
    const int oi = tid >> 2, oc = (tid & 3) << 4;    // 128 rows x 64 cols
    _Float16* dst = &ctx[((size_t)n * TSEQ + q0 + oi) * DM + h * HD + oc];
    *(half8*)&dst[0] = *(const half8*)&Osh[oi * 72 + oc];
    *(half8*)&dst[8] = *(const half8*)&Osh[oi * 72 + oc + 8];
  }
}

// ---------------- output projection (f16 MFMA) + bias, f32 out ------------------
// R11 (kept): qkv-style global_load_lds double-buffered pipeline.
__global__ __launch_bounds__(256) void out_gemm_mfma(
    const _Float16* __restrict__ A, const _Float16* __restrict__ B,
    const float* __restrict__ bias, float* __restrict__ out)
{
  __shared__ __align__(16) _Float16 As0[128 * 32];
  __shared__ __align__(16) _Float16 Bs0[64 * 32];
  __shared__ __align__(16) _Float16 As1[128 * 32];
  __shared__ __align__(16) _Float16 Bs1[64 * 32];
  const int tid = threadIdx.x;
  const int wv = tid >> 6, lane = tid & 63, quad = lane >> 4, col = lane & 15;
  const int wm = wv >> 1, we = wv & 1;
  const int m0 = blockIdx.x << 7, c0 = blockIdx.y << 6;
  const int r0 = tid >> 2, p0 = tid & 3;
  const int cA0 = (p0 - (r0 >> 1)) & 3;
  const int r1 = (tid + 256) >> 2;
  const int cA1 = (p0 - (r1 >> 1)) & 3;
  const _Float16* ga0 = &A[(size_t)(m0 + r0) * DM + cA0 * 8];
  const _Float16* ga1 = &A[(size_t)(m0 + r1) * DM + cA1 * 8];
  const _Float16* gb0 = &B[(size_t)(c0 + r0) * DM + cA0 * 8];   // 64 rows, 4 phases
  floatx4 acc[4][2] = {};

#define OG_STAGE(AS, BS, K)                       \
  do {                                            \
    gl2lds16(ga0 + (K), &AS[tid * 8]);            \
    gl2lds16(ga1 + (K), &AS[(tid + 256) * 8]);    \
    gl2lds16(gb0 + (K), &BS[tid * 8]);            \
  } while (0)

#define OG_COMPUTE(AS, BS)                                                    \
  do {                                                                        \
    half8 af[4], bf[2];                                                       \
    _Pragma("unroll") for (int mt = 0; mt < 4; mt++) {                        \
      const int R = wm * 64 + mt * 16 + col;                                  \
      af[mt] = *(const half8*)&AS[R * 32 + (((quad + (R >> 1)) & 3) << 3)];   \
    }                                                                         \
    _Pragma("unroll") for (int et = 0; et < 2; et++) {                        \
      const int R = we * 32 + et * 16 + col;                                  \
      bf[et] = *(const half8*)&BS[R * 32 + (((quad + (R >> 1)) & 3) << 3)];   \
    }                                                                         \
    _Pragma("unroll") for (int mt = 0; mt < 4; mt++)                          \
      _Pragma("unroll") for (int et = 0; et < 2; et++)                        \
        acc[mt][et] =                                                         \
            __builtin_amdgcn_mfma_f32_16x16x32_f16(af[mt], bf[et], acc[mt][et], 0, 0, 0); \
  } while (0)

  OG_STAGE(As0, Bs0, 0);
  for (int k0 = 0; k0 < DM; k0 += 64) {
    __syncthreads();                    // buf0(k0) landed & visible; prev reads done
    OG_STAGE(As1, Bs1, k0 + 32);
    OG_COMPUTE(As0, Bs0);
    __syncthreads();
    if (k0 + 64 < DM) OG_STAGE(As0, Bs0, k0 + 64);
    OG_COMPUTE(As1, Bs1);
  }
#undef OG_STAGE
#undef OG_COMPUTE

  float bb[2];
#pragma unroll
  for (int et = 0; et < 2; et++) bb[et] = bias[c0 + we * 32 + et * 16 + col];
  const int mbase = m0 + wm * 64 + quad * 4;
#pragma unroll
  for (int mt = 0; mt < 4; mt++)
#pragma unroll
    for (int r = 0; r < 4; r++) {
      const int m = mbase + mt * 16 + r;
#pragma unroll
      for (int et = 0; et < 2; et++)
        out[(size_t)m * DM + c0 + we * 32 + et * 16 + col] = acc[mt][et][r] + bb[et];
    }
}

extern "C" void kernel_launch(void* const* d_in, const int* in_sizes, int n_in,
                              void* d_out, int out_size, void* d_ws, size_t ws_size,
                              hipStream_t stream) {
  const float* x    = (const float*)d_in[0];
  const float* wqkv = (const float*)d_in[1];
  const float* ow   = (const float*)d_in[2];
  const float* ob   = (const float*)d_in[3];
  char* ws = (char*)d_ws;
  _Float16* xh    = (_Float16*)(ws);               //  8,388,608 B
  _Float16* wqkvh = (_Float16*)(ws + 8650752);     //  1,572,864 B
  _Float16* owh   = (_Float16*)(ws + 10485760);    //    524,288 B
  _Float16* qbuf  = (_Float16*)(ws + 11534336);    //  8,388,608 B
  _Float16* kbuf  = (_Float16*)(ws + 20971520);    //  8,388,608 B
  _Float16* vTb   = (_Float16*)(ws + 29360128);    //  8,388,608 B
  _Float16* ctxh  = (_Float16*)(ws + 37748736);    //  8,388,608 B
  float2*   rope  = (float2*)  (ws + 46137344);    //    524,288 B -> end 46,661,632

  prep<<<2688, 256, 0, stream>>>(x, wqkv, ow, ws);        // 688128 16B-units, 1/thread
  qkv_gemm_mfma<<<dim3(64, 12), 256, 0, stream>>>(xh, wqkvh, rope, qbuf, kbuf, vTb);
  attn_win_mfma<<<dim3(16, 32), 512, 0, stream>>>(qbuf, kbuf, vTb, ctxh);
  out_gemm_mfma<<<dim3(64, 8), 256, 0, stream>>>(ctxh, owh, ob, (float*)d_out);
}